// Round 8
// baseline (1389.999 us; speedup 1.0000x reference)
//
#include <hip/hip_runtime.h>
#include <hip/hip_bf16.h>
#include <cstdint>

#define NPTS (1u << 20)
#define CDIM 128
#define NSEG 4096
#define NBLK 16384  // 64-row GEMM blocks

typedef __attribute__((ext_vector_type(8))) short short8;
typedef __attribute__((ext_vector_type(4))) float f32x4;

// ---- static device workspace (no allocation inside kernel_launch; graph
// capture sees only kernel nodes -> deterministic replay, r7-verified)
#define H_BYTES   268435456ull                 // 1M x 128 bf16 activations (in-place)
#define STL_OFF   H_BYTES                      // s_last[128], t_last[128]
#define WT_OFF    (STL_OFF + 1024)             // folded W'T bf16 [128][128]
#define BP_OFF    (WT_OFF + 32768)             // folded b' [128]
#define MAXB_OFF  (BP_OFF + 512)               // [16384][128] f32 per-64-row max
#define MINB_OFF  (MAXB_OFF + 8388608ull)      // [16384][128] f32
#define PART_OFF  (MINB_OFF + 8388608ull)      // partials [16384][256] f32
#define P2_OFF    (PART_OFF + 16777216ull)     // partial2 [64][256] f32
#define WS_TOTAL  (P2_OFF + 65536ull)

__device__ __align__(256) unsigned char g_ws[WS_TOTAL];

__device__ __forceinline__ uint32_t bf16rne(float f) {
    uint32_t u = __float_as_uint(f);
    return (u + 0x7fffu + ((u >> 16) & 1u)) >> 16;
}
__device__ __forceinline__ uint32_t pack2(float a, float b) {
    union { __hip_bfloat162 h; uint32_t u; } cv;
    cv.h = __float22bfloat162_rn(make_float2(a, b));  // v_cvt_pk_bf16_f32 RNE
    return cv.u;
}
// mish(x) = x*(t^2+2t)/(t^2+2t+2), t=e^x (exact identity)
__device__ __forceinline__ float mish_f(float x) {
    float t = __expf(x);
    float u = t * (t + 2.0f);
    float m = x * u * __builtin_amdgcn_rcpf(u + 2.0f);
    return (x > 15.0f) ? x : m;
}

// ---------------- k0: h0 = mish(points @ w_first + b_first) (bf16) + partial stats
// 64 rows per block; fused single-pass stats reduce (2 barriers)
__global__ __launch_bounds__(256) void k_first(const float2* __restrict__ pts,
                                               const float* __restrict__ wf,
                                               const float* __restrict__ bf) {
    uint16_t* hout = (uint16_t*)g_ws;
    float* partials = (float*)(g_ws + PART_OFF);
    int tid = threadIdx.x;
    int colg = tid & 15;   // channels colg*8..+8
    int rowt = tid >> 4;   // 16 row-threads
    float w0[8], w1[8], bb[8];
#pragma unroll
    for (int e = 0; e < 8; e++) {
        w0[e] = wf[colg * 8 + e];
        w1[e] = wf[128 + colg * 8 + e];
        bb[e] = bf[colg * 8 + e];
    }
    float ssum[8], ssq[8];
#pragma unroll
    for (int e = 0; e < 8; e++) { ssum[e] = 0.f; ssq[e] = 0.f; }

    int base = blockIdx.x * 64;
    for (int p = 0; p < 4; p++) {
        int pi = base + p * 16 + rowt;
        float2 pt = pts[pi];
        float v[8];
#pragma unroll
        for (int e = 0; e < 8; e++) {
            float x = fmaf(pt.x, w0[e], fmaf(pt.y, w1[e], bb[e]));
            v[e] = mish_f(x);
            ssum[e] += v[e];
            ssq[e] += v[e] * v[e];
        }
        uint4 o;
        o.x = pack2(v[0], v[1]); o.y = pack2(v[2], v[3]);
        o.z = pack2(v[4], v[5]); o.w = pack2(v[6], v[7]);
        *(uint4*)(hout + (size_t)pi * CDIM + colg * 8) = o;
    }
    __shared__ float red[4096];
#pragma unroll
    for (int e = 0; e < 8; e++) {
        red[tid * 8 + e] = ssum[e];
        red[2048 + tid * 8 + e] = ssq[e];
    }
    __syncthreads();
    if (tid < 128) {
        int cg = tid >> 3, e = tid & 7;  // channel cg*8+e == tid
        float a = 0.f, q = 0.f;
#pragma unroll
        for (int r = 0; r < 16; r++) {
            int i = (cg + (r << 4)) * 8 + e;
            a += red[i];
            q += red[2048 + i];
        }
        partials[(size_t)blockIdx.x * 256 + tid] = a;
        partials[(size_t)blockIdx.x * 256 + 128 + tid] = q;
    }
}

// ---------------- GEMM: X = h @ W' + b'  (swapped MFMA: A=W'T frags, B=h frags)
// 64 rows per block, grid 16384 -> 4 blocks/CU resident, phases of different
// blocks overlap (r7 diagnosis: 256-row blocks with 8 barriers serialised at
// occ 20%, all pipes ~1/3 idle). One barrier + fused 2-barrier stats reduce.
// MODE 0: in-place h = mish(X) bf16 + partial stats of mish(X)
// MODE 1: no store; partial stats of X + per-64-row max/min of X
// NOTE: (256,2) bounds; (256,4) forced VGPR=64 + scratch spill in r3.
template <int MODE>
__global__ __launch_bounds__(256, 2) void k_gemm() {
    uint16_t* hbuf = (uint16_t*)g_ws;
    const uint16_t* wt = (const uint16_t*)(g_ws + WT_OFF);
    const float* bp = (const float*)(g_ws + BP_OFF);
    float* partials = (float*)(g_ws + PART_OFF);
    float* maxb = (float*)(g_ws + MAXB_OFF);
    float* minb = (float*)(g_ws + MINB_OFF);

    int tid = threadIdx.x;
    int lane = tid & 63;
    int wave = tid >> 6;
    int l15 = lane & 15;
    int l4 = lane >> 4;

    size_t rowbase = (size_t)blockIdx.x * 64;

    // issue A-loads (HBM/L3) first so their latency overlaps the L2 weight loads
    short8 af[4];
    {
        const uint16_t* ap = hbuf + (rowbase + wave * 16 + l15) * CDIM + l4 * 8;
#pragma unroll
        for (int kk = 0; kk < 4; kk++) af[kk] = *(const short8*)(ap + kk * 32);
    }
    short8 bfrag[8][4];
#pragma unroll
    for (int jb = 0; jb < 8; jb++)
#pragma unroll
        for (int kk = 0; kk < 4; kk++)
            bfrag[jb][kk] = *(const short8*)(wt + (jb * 16 + l15) * CDIM + kk * 32 + l4 * 8);

    float bias_r[8];
#pragma unroll
    for (int e = 0; e < 8; e++) bias_r[e] = bp[(tid & 15) * 8 + e];

    f32x4 acc[8];
#pragma unroll
    for (int jb = 0; jb < 8; jb++) acc[jb] = (f32x4){0.f, 0.f, 0.f, 0.f};
#pragma unroll
    for (int kk = 0; kk < 4; kk++)
#pragma unroll
        for (int jb = 0; jb < 8; jb++)
            acc[jb] = __builtin_amdgcn_mfma_f32_16x16x32_bf16(bfrag[jb][kk], af[kk], acc[jb], 0, 0, 0);

    // D[j][m]: col=l15=point, row j=jb*16+l4*4+r -> ds_write_b128 per jb
    __shared__ float sm[64 * 132];
#pragma unroll
    for (int jb = 0; jb < 8; jb++)
        *(f32x4*)&sm[(wave * 16 + l15) * 132 + jb * 16 + l4 * 4] = acc[jb];
    __syncthreads();

    float ssum[8], ssq[8], smax[8], smin[8];
#pragma unroll
    for (int e = 0; e < 8; e++) {
        ssum[e] = 0.f; ssq[e] = 0.f;
        smax[e] = -3.4e38f; smin[e] = 3.4e38f;
    }

    // readout: thread t -> rows (t>>4)+16*it, channels (t&15)*8..+8
    int rt = tid >> 4, cg = tid & 15;
#pragma unroll
    for (int it = 0; it < 4; ++it) {
        int lr = rt + (it << 4);
        const float4* rp = (const float4*)&sm[lr * 132 + cg * 8];
        float4 v0 = rp[0], v1 = rp[1];
        float v[8] = {v0.x, v0.y, v0.z, v0.w, v1.x, v1.y, v1.z, v1.w};
#pragma unroll
        for (int e = 0; e < 8; e++) v[e] += bias_r[e];
        if constexpr (MODE == 0) {
#pragma unroll
            for (int e = 0; e < 8; e++) v[e] = mish_f(v[e]);
            uint4 o;
            o.x = pack2(v[0], v[1]); o.y = pack2(v[2], v[3]);
            o.z = pack2(v[4], v[5]); o.w = pack2(v[6], v[7]);
            *(uint4*)(hbuf + (rowbase + lr) * CDIM + cg * 8) = o;
        }
#pragma unroll
        for (int e = 0; e < 8; e++) {
            ssum[e] += v[e];
            ssq[e] += v[e] * v[e];
        }
        if constexpr (MODE == 1) {
#pragma unroll
            for (int e = 0; e < 8; e++) {
                smax[e] = fmaxf(smax[e], v[e]);
                smin[e] = fminf(smin[e], v[e]);
            }
        }
    }
    __syncthreads();  // sm reads done before reuse as reduce scratch

    // fused single-pass stats reduce (sum/sq[/max/min]) in sm (needs <=32KB)
#pragma unroll
    for (int e = 0; e < 8; e++) {
        sm[tid * 8 + e] = ssum[e];
        sm[2048 + tid * 8 + e] = ssq[e];
    }
    if constexpr (MODE == 1) {
#pragma unroll
        for (int e = 0; e < 8; e++) {
            sm[4096 + tid * 8 + e] = smax[e];
            sm[6144 + tid * 8 + e] = smin[e];
        }
    }
    __syncthreads();
    if (tid < 128) {
        int cg2 = tid >> 3, e = tid & 7;  // channel == tid
        float a = 0.f, q = 0.f, mx = -3.4e38f, mn = 3.4e38f;
#pragma unroll
        for (int r = 0; r < 16; r++) {
            int i = (cg2 + (r << 4)) * 8 + e;
            a += sm[i];
            q += sm[2048 + i];
            if (MODE == 1) {
                mx = fmaxf(mx, sm[4096 + i]);
                mn = fminf(mn, sm[6144 + i]);
            }
        }
        partials[(size_t)blockIdx.x * 256 + tid] = a;
        partials[(size_t)blockIdx.x * 256 + 128 + tid] = q;
        if (MODE == 1) {
            maxb[(size_t)blockIdx.x * 128 + tid] = mx;
            minb[(size_t)blockIdx.x * 128 + tid] = mn;
        }
    }
}

// ---------------- deterministic stage-1 reduce: partials[16384][256] -> partial2[64][256]
__global__ __launch_bounds__(256) void k_reduce1() {
    const float* partials = (const float*)(g_ws + PART_OFF);
    float* partial2 = (float*)(g_ws + P2_OFF);
    int c = threadIdx.x;
    int r0 = blockIdx.x * 256;
    float a = 0.f;
    for (int r = 0; r < 256; r++) a += partials[(size_t)(r0 + r) * 256 + c];
    partial2[blockIdx.x * 256 + c] = a;
}

// ---------------- fold BN into next linear; includes stage-2 stats reduce.
// block j (128 blocks), 256 threads: wt[j][k]=s[k]W[k][j] bf16, b'[j]=b[j]+sum t[k]W[k][j]
__global__ __launch_bounds__(256) void k_fold(int L,
                                              const float* __restrict__ gamma_all, const float* __restrict__ beta_all,
                                              const float* __restrict__ W_all, const float* __restrict__ b_all) {
    const float* partial2 = (const float*)(g_ws + P2_OFF);
    uint16_t* wtt = (uint16_t*)(g_ws + WT_OFF);
    float* bpp = (float*)(g_ws + BP_OFF);
    const float* gamma = gamma_all + L * 128;
    const float* beta = beta_all + L * 128;
    const float* W = W_all + (size_t)L * 16384;
    const float* b = b_all + L * 128;

    __shared__ float sstats[256];
    __shared__ float sv[128], tv[128], red[128];
    int t = threadIdx.x;
    float a = 0.f;
    for (int r = 0; r < 64; r++) a += partial2[r * 256 + t];
    sstats[t] = a;
    __syncthreads();
    if (t < 128) {
        float mean = sstats[t] * (1.0f / (float)NPTS);
        float var = sstats[128 + t] * (1.0f / (float)NPTS) - mean * mean;
        float s = gamma[t] * rsqrtf(var + 1e-5f);
        sv[t] = s;
        tv[t] = beta[t] - mean * s;
    }
    __syncthreads();
    int j = blockIdx.x;
    if (t < 128) {
        float w = W[t * 128 + j];
        wtt[j * 128 + t] = (uint16_t)bf16rne(sv[t] * w);
        red[t] = tv[t] * w;
    }
    __syncthreads();
#pragma unroll
    for (int off = 64; off >= 1; off >>= 1) {
        if (t < off) red[t] += red[t + off];
        __syncthreads();
    }
    if (t == 0) bpp[j] = b[j] + red[0];
}

// ---------------- last BN scale/shift (includes stage-2 reduce)
__global__ __launch_bounds__(256) void k_lastbn(const float* __restrict__ gamma,
                                                const float* __restrict__ beta) {
    const float* partial2 = (const float*)(g_ws + P2_OFF);
    float* st = (float*)(g_ws + STL_OFF);
    __shared__ float sstats[256];
    int t = threadIdx.x;
    float a = 0.f;
    for (int r = 0; r < 64; r++) a += partial2[r * 256 + t];
    sstats[t] = a;
    __syncthreads();
    if (t < 128) {
        float mean = sstats[t] * (1.0f / (float)NPTS);
        float var = sstats[128 + t] * (1.0f / (float)NPTS) - mean * mean;
        float s = gamma[t] * rsqrtf(var + 1e-5f);
        st[t] = s;
        st[128 + t] = beta[t] - mean * s;
    }
}

// ---------------- finalize: combine 4 per-64-row max/min blocks per segment
__global__ __launch_bounds__(256) void k_final(float* __restrict__ out) {
    const float* maxb = (const float*)(g_ws + MAXB_OFF);
    const float* minb = (const float*)(g_ws + MINB_OFF);
    const float* st = (const float*)(g_ws + STL_OFF);
    int idx = blockIdx.x * 256 + threadIdx.x;
    int c = idx & 127;
    int seg = idx >> 7;
    float s = st[c], t = st[128 + c];
    float r;
    if (s >= 0.f) {
        r = maxb[(size_t)(seg * 4) * 128 + c];
#pragma unroll
        for (int i = 1; i < 4; i++) r = fmaxf(r, maxb[(size_t)(seg * 4 + i) * 128 + c]);
    } else {
        r = minb[(size_t)(seg * 4) * 128 + c];
#pragma unroll
        for (int i = 1; i < 4; i++) r = fminf(r, minb[(size_t)(seg * 4 + i) * 128 + c]);
    }
    out[idx] = fmaf(s, r, t);
}

extern "C" void kernel_launch(void* const* d_in, const int* in_sizes, int n_in,
                              void* d_out, int out_size, void* d_ws, size_t ws_size,
                              hipStream_t stream) {
    const float2* pts = (const float2*)d_in[0];
    // d_in[1] segment_ids: contiguous equal segments of 256 -> implicit
    const float* wf = (const float*)d_in[2];
    const float* bfirst = (const float*)d_in[3];
    const float* mg = (const float*)d_in[4];
    const float* mb = (const float*)d_in[5];
    const float* mw = (const float*)d_in[6];
    const float* mbi = (const float*)d_in[7];
    const float* lg = (const float*)d_in[8];
    const float* lb = (const float*)d_in[9];
    float* out = (float*)d_out;

    k_first<<<NBLK, 256, 0, stream>>>(pts, wf, bfirst);
    k_reduce1<<<64, 256, 0, stream>>>();
    for (int L = 0; L < 4; ++L) {
        k_fold<<<128, 256, 0, stream>>>(L, mg, mb, mw, mbi);
        if (L < 3)
            k_gemm<0><<<NBLK, 256, 0, stream>>>();
        else
            k_gemm<1><<<NBLK, 256, 0, stream>>>();
        k_reduce1<<<64, 256, 0, stream>>>();
    }
    k_lastbn<<<256, 256, 0, stream>>>(lg, lb);
    k_final<<<2048, 256, 0, stream>>>(out);
}

// Round 9
// 611.206 us; speedup vs baseline: 2.2742x; 2.2742x over previous
//
#include <hip/hip_runtime.h>
#include <hip/hip_bf16.h>
#include <cstdint>

#define NPTS (1u << 20)
#define CDIM 128
#define NSEG 4096

typedef __attribute__((ext_vector_type(8))) short short8;
typedef __attribute__((ext_vector_type(4))) float f32x4;

// ---- static device workspace (graph capture sees only kernel nodes; r7-verified)
#define H_BYTES   268435456ull                 // 1M x 128 bf16 activations (in-place)
#define STL_OFF   H_BYTES                      // s_last[128], t_last[128]
#define WT_OFF    (STL_OFF + 1024)             // folded W'T bf16 [128][128]
#define BP_OFF    (WT_OFF + 32768)             // folded b' [128]
#define MAXB_OFF  (BP_OFF + 512)               // [4096][128] f32 per-segment max
#define MINB_OFF  (MAXB_OFF + 2097152ull)      // [4096][128] f32
#define PART_OFF  (MINB_OFF + 2097152ull)      // partials [4096][256] f32
#define P2_OFF    (PART_OFF + 4194304ull)      // partial2 [64][256] f32
#define WS_TOTAL  (P2_OFF + 65536ull)

__device__ __align__(256) unsigned char g_ws[WS_TOTAL];

__device__ __forceinline__ uint32_t bf16rne(float f) {
    uint32_t u = __float_as_uint(f);
    return (u + 0x7fffu + ((u >> 16) & 1u)) >> 16;
}
__device__ __forceinline__ uint32_t pack2(float a, float b) {
    union { __hip_bfloat162 h; uint32_t u; } cv;
    cv.h = __float22bfloat162_rn(make_float2(a, b));  // v_cvt_pk_bf16_f32 RNE
    return cv.u;
}
__device__ __forceinline__ float upk(uint32_t u, int hi) {
    return __uint_as_float((hi ? (u & 0xffff0000u) : (u << 16)));
}
// mish(x) = x*(t^2+2t)/(t^2+2t+2), t=e^x (exact identity)
__device__ __forceinline__ float mish_f(float x) {
    float t = __expf(x);
    float u = t * (t + 2.0f);
    float m = x * u * __builtin_amdgcn_rcpf(u + 2.0f);
    return (x > 15.0f) ? x : m;
}

// ---------------- k0: h0 = mish(points @ w_first + b_first) (bf16) + partial stats
__global__ __launch_bounds__(256) void k_first(const float2* __restrict__ pts,
                                               const float* __restrict__ wf,
                                               const float* __restrict__ bf) {
    uint16_t* hout = (uint16_t*)g_ws;
    float* partials = (float*)(g_ws + PART_OFF);
    int tid = threadIdx.x;
    int colg = tid & 15;
    int rowt = tid >> 4;
    float w0[8], w1[8], bb[8];
#pragma unroll
    for (int e = 0; e < 8; e++) {
        w0[e] = wf[colg * 8 + e];
        w1[e] = wf[128 + colg * 8 + e];
        bb[e] = bf[colg * 8 + e];
    }
    float ssum[8], ssq[8];
#pragma unroll
    for (int e = 0; e < 8; e++) { ssum[e] = 0.f; ssq[e] = 0.f; }

    int base = blockIdx.x * 256;
    for (int p = 0; p < 16; p++) {
        int pi = base + p * 16 + rowt;
        float2 pt = pts[pi];
        float v[8];
#pragma unroll
        for (int e = 0; e < 8; e++) {
            float x = fmaf(pt.x, w0[e], fmaf(pt.y, w1[e], bb[e]));
            v[e] = mish_f(x);
            ssum[e] += v[e];
            ssq[e] += v[e] * v[e];
        }
        uint4 o;
        o.x = pack2(v[0], v[1]); o.y = pack2(v[2], v[3]);
        o.z = pack2(v[4], v[5]); o.w = pack2(v[6], v[7]);
        *(uint4*)(hout + (size_t)pi * CDIM + colg * 8) = o;
    }
    __shared__ float red[4096];
#pragma unroll
    for (int e = 0; e < 8; e++) {
        red[tid * 8 + e] = ssum[e];
        red[2048 + tid * 8 + e] = ssq[e];
    }
    __syncthreads();
    if (tid < 128) {
        int cg = tid >> 3, e = tid & 7;
        float a = 0.f, q = 0.f;
#pragma unroll
        for (int r = 0; r < 16; r++) {
            int i = (cg + (r << 4)) * 8 + e;
            a += red[i];
            q += red[2048 + i];
        }
        partials[(size_t)blockIdx.x * 256 + tid] = a;
        partials[(size_t)blockIdx.x * 256 + 128 + tid] = q;
    }
}

// ---------------- GEMM: X = h @ W' + b'
// r8 post-mortem: bfrag[8][4] needs 128 VGPR; at VGPR=52/112 the compiler
// re-streamed weight loads inside the MFMA loop -> serial L2-latency chain
// (the 153-312us floor; MODE0==MODE1 invariance). FIX: weights in LDS
// (XOR-swizzled rows, G4: stride-256B rows are 16-way conflicts otherwise),
// double-buffered ds_read_b128 -> pipelined at throughput, not latency.
// Epilogue stages BF16 (mish+pack in MFMA layout) -> 17.4KB stage; total LDS
// 50KB -> 3 blocks/CU. Dead weight-LDS reused as stats scratch at the end.
// MODE 0: in-place h = mish(X) bf16 + partial stats; MODE 1: stats + seg max/min.
template <int MODE>
__global__ __launch_bounds__(256, 1) void k_gemm() {
    uint16_t* hbuf = (uint16_t*)g_ws;
    const uint16_t* wt = (const uint16_t*)(g_ws + WT_OFF);
    const float* bp = (const float*)(g_ws + BP_OFF);
    float* partials = (float*)(g_ws + PART_OFF);
    float* maxb = (float*)(g_ws + MAXB_OFF);
    float* minb = (float*)(g_ws + MINB_OFF);

    __shared__ uint16_t wlds[16384];      // swizzled W'T [128 rows][256 B]
    __shared__ uint32_t sm16[64 * 68];    // bf16-pair stage [64 pts][64+4 pad u32]

    int tid = threadIdx.x;
    int lane = tid & 63;
    int wave = tid >> 6;
    int l15 = lane & 15;
    int l4 = lane >> 4;

    // stage W'T global->LDS, row-XOR swizzle: byte col cb ^= (row&7)<<4
    {
        const uint4* src = (const uint4*)wt;
#pragma unroll
        for (int i = 0; i < 8; i++) {
            int idx = i * 256 + tid;          // uint4 index; 16 per row
            int row = idx >> 4;
            int cb = (idx & 15) << 4;
            uint4 v = src[idx];
            *(uint4*)((char*)wlds + row * 256 + (cb ^ ((row & 7) << 4))) = v;
        }
    }

    size_t rowbase = (size_t)blockIdx.x * 256;
    short8 af[4], afn[4];
    {
        const uint16_t* ap = hbuf + (rowbase + wave * 16 + l15) * CDIM + l4 * 8;
#pragma unroll
        for (int kk = 0; kk < 4; kk++) af[kk] = *(const short8*)(ap + kk * 32);
    }

    float ssum[8], ssq[8], smax[8], smin[8];
#pragma unroll
    for (int e = 0; e < 8; e++) {
        ssum[e] = 0.f; ssq[e] = 0.f;
        smax[e] = -3.4e38f; smin[e] = 3.4e38f;
    }

    int swz = (l15 & 7) << 4;  // row-dependent XOR for this lane's weight rows

#define WREAD(dst, kkv)                                                              \
    {                                                                                \
        _Pragma("unroll") for (int jb = 0; jb < 8; jb++) {                           \
            int cb = (((kkv)*64 + l4 * 16) ^ swz);                                   \
            dst[jb] = *(const short8*)((const char*)wlds + (jb * 16 + l15) * 256 + cb); \
        }                                                                            \
    }

    __syncthreads();  // wlds ready

    for (int g = 0; g < 4; ++g) {
        if (g < 3) {
            const uint16_t* ap = hbuf + (rowbase + (size_t)(g + 1) * 64 + wave * 16 + l15) * CDIM + l4 * 8;
#pragma unroll
            for (int kk = 0; kk < 4; kk++) afn[kk] = *(const short8*)(ap + kk * 32);
        }
        f32x4 acc[8];
#pragma unroll
        for (int jb = 0; jb < 8; jb++) acc[jb] = *(const f32x4*)&bp[jb * 16 + l4 * 4];

        short8 wa[8], wb[8];
        WREAD(wa, 0);
        WREAD(wb, 1);
#pragma unroll
        for (int jb = 0; jb < 8; jb++)
            acc[jb] = __builtin_amdgcn_mfma_f32_16x16x32_bf16(wa[jb], af[0], acc[jb], 0, 0, 0);
        WREAD(wa, 2);
#pragma unroll
        for (int jb = 0; jb < 8; jb++)
            acc[jb] = __builtin_amdgcn_mfma_f32_16x16x32_bf16(wb[jb], af[1], acc[jb], 0, 0, 0);
        WREAD(wb, 3);
#pragma unroll
        for (int jb = 0; jb < 8; jb++)
            acc[jb] = __builtin_amdgcn_mfma_f32_16x16x32_bf16(wa[jb], af[2], acc[jb], 0, 0, 0);
#pragma unroll
        for (int jb = 0; jb < 8; jb++)
            acc[jb] = __builtin_amdgcn_mfma_f32_16x16x32_bf16(wb[jb], af[3], acc[jb], 0, 0, 0);

        // mish (MODE0) + pack to bf16 in MFMA layout; lane owns 4 consecutive
        // channels (jb*16+l4*4..+4) of point l15 -> ds_write_b64 per jb
#pragma unroll
        for (int jb = 0; jb < 8; jb++) {
            float v0 = acc[jb][0], v1 = acc[jb][1], v2 = acc[jb][2], v3 = acc[jb][3];
            if (MODE == 0) {
                v0 = mish_f(v0); v1 = mish_f(v1); v2 = mish_f(v2); v3 = mish_f(v3);
            }
            uint2 pk;
            pk.x = pack2(v0, v1);
            pk.y = pack2(v2, v3);
            *(uint2*)&sm16[(wave * 16 + l15) * 68 + jb * 8 + l4 * 2] = pk;
        }
        __syncthreads();

        // readout: thread t -> rows (t>>4)+16*it, channels (t&15)*8..+8 (bf16 pairs)
        int rt = tid >> 4, cg = tid & 15;
#pragma unroll
        for (int it = 0; it < 4; ++it) {
            int lr = rt + (it << 4);
            uint4 o = *(const uint4*)&sm16[lr * 68 + cg * 4];
            if constexpr (MODE == 0)
                *(uint4*)(hbuf + (rowbase + (size_t)g * 64 + lr) * CDIM + cg * 8) = o;
            uint32_t w[4] = {o.x, o.y, o.z, o.w};
#pragma unroll
            for (int h = 0; h < 4; h++) {
#pragma unroll
                for (int hi = 0; hi < 2; hi++) {
                    float x = upk(w[h], hi);
                    int e = h * 2 + hi;
                    ssum[e] += x;
                    ssq[e] += x * x;
                    if (MODE == 1) {
                        smax[e] = fmaxf(smax[e], x);
                        smin[e] = fminf(smin[e], x);
                    }
                }
            }
        }
        __syncthreads();
        if (g < 3) {
#pragma unroll
            for (int kk = 0; kk < 4; kk++) af[kk] = afn[kk];
        }
    }

    // fused stats reduce in the now-dead weight LDS (32 KB = 8192 floats)
    float* redf = (float*)wlds;
#pragma unroll
    for (int e = 0; e < 8; e++) {
        redf[tid * 8 + e] = ssum[e];
        redf[2048 + tid * 8 + e] = ssq[e];
    }
    if constexpr (MODE == 1) {
#pragma unroll
        for (int e = 0; e < 8; e++) {
            redf[4096 + tid * 8 + e] = smax[e];
            redf[6144 + tid * 8 + e] = smin[e];
        }
    }
    __syncthreads();
    if (tid < 128) {
        int cg2 = tid >> 3, e = tid & 7;
        float a = 0.f, q = 0.f, mx = -3.4e38f, mn = 3.4e38f;
#pragma unroll
        for (int r = 0; r < 16; r++) {
            int i = (cg2 + (r << 4)) * 8 + e;
            a += redf[i];
            q += redf[2048 + i];
            if (MODE == 1) {
                mx = fmaxf(mx, redf[4096 + i]);
                mn = fminf(mn, redf[6144 + i]);
            }
        }
        partials[(size_t)blockIdx.x * 256 + tid] = a;
        partials[(size_t)blockIdx.x * 256 + 128 + tid] = q;
        if (MODE == 1) {
            maxb[(size_t)blockIdx.x * 128 + tid] = mx;
            minb[(size_t)blockIdx.x * 128 + tid] = mn;
        }
    }
#undef WREAD
}

// ---------------- deterministic stage-1 reduce: partials[4096][256] -> partial2[64][256]
__global__ __launch_bounds__(256) void k_reduce1() {
    const float* partials = (const float*)(g_ws + PART_OFF);
    float* partial2 = (float*)(g_ws + P2_OFF);
    int c = threadIdx.x;
    int r0 = blockIdx.x * 64;
    float a = 0.f;
    for (int r = 0; r < 64; r++) a += partials[(size_t)(r0 + r) * 256 + c];
    partial2[blockIdx.x * 256 + c] = a;
}

// ---------------- fold BN into next linear; includes stage-2 stats reduce.
__global__ __launch_bounds__(256) void k_fold(int L,
                                              const float* __restrict__ gamma_all, const float* __restrict__ beta_all,
                                              const float* __restrict__ W_all, const float* __restrict__ b_all) {
    const float* partial2 = (const float*)(g_ws + P2_OFF);
    uint16_t* wtt = (uint16_t*)(g_ws + WT_OFF);
    float* bpp = (float*)(g_ws + BP_OFF);
    const float* gamma = gamma_all + L * 128;
    const float* beta = beta_all + L * 128;
    const float* W = W_all + (size_t)L * 16384;
    const float* b = b_all + L * 128;

    __shared__ float sstats[256];
    __shared__ float sv[128], tv[128], red[128];
    int t = threadIdx.x;
    float a = 0.f;
    for (int r = 0; r < 64; r++) a += partial2[r * 256 + t];
    sstats[t] = a;
    __syncthreads();
    if (t < 128) {
        float mean = sstats[t] * (1.0f / (float)NPTS);
        float var = sstats[128 + t] * (1.0f / (float)NPTS) - mean * mean;
        float s = gamma[t] * rsqrtf(var + 1e-5f);
        sv[t] = s;
        tv[t] = beta[t] - mean * s;
    }
    __syncthreads();
    int j = blockIdx.x;
    if (t < 128) {
        float w = W[t * 128 + j];
        wtt[j * 128 + t] = (uint16_t)bf16rne(sv[t] * w);
        red[t] = tv[t] * w;
    }
    __syncthreads();
#pragma unroll
    for (int off = 64; off >= 1; off >>= 1) {
        if (t < off) red[t] += red[t + off];
        __syncthreads();
    }
    if (t == 0) bpp[j] = b[j] + red[0];
}

// ---------------- last BN scale/shift (includes stage-2 reduce)
__global__ __launch_bounds__(256) void k_lastbn(const float* __restrict__ gamma,
                                                const float* __restrict__ beta) {
    const float* partial2 = (const float*)(g_ws + P2_OFF);
    float* st = (float*)(g_ws + STL_OFF);
    __shared__ float sstats[256];
    int t = threadIdx.x;
    float a = 0.f;
    for (int r = 0; r < 64; r++) a += partial2[r * 256 + t];
    sstats[t] = a;
    __syncthreads();
    if (t < 128) {
        float mean = sstats[t] * (1.0f / (float)NPTS);
        float var = sstats[128 + t] * (1.0f / (float)NPTS) - mean * mean;
        float s = gamma[t] * rsqrtf(var + 1e-5f);
        st[t] = s;
        st[128 + t] = beta[t] - mean * s;
    }
}

// ---------------- finalize: out[seg][c] = s*(s>=0 ? max : min) + t (block==segment)
__global__ __launch_bounds__(256) void k_final(float* __restrict__ out) {
    const float* maxb = (const float*)(g_ws + MAXB_OFF);
    const float* minb = (const float*)(g_ws + MINB_OFF);
    const float* st = (const float*)(g_ws + STL_OFF);
    int idx = blockIdx.x * 256 + threadIdx.x;
    int c = idx & 127;
    float s = st[c], t = st[128 + c];
    out[idx] = fmaf(s, (s >= 0.f ? maxb[idx] : minb[idx]), t);
}

extern "C" void kernel_launch(void* const* d_in, const int* in_sizes, int n_in,
                              void* d_out, int out_size, void* d_ws, size_t ws_size,
                              hipStream_t stream) {
    const float2* pts = (const float2*)d_in[0];
    // d_in[1] segment_ids: contiguous equal segments of 256 -> implicit
    const float* wf = (const float*)d_in[2];
    const float* bfirst = (const float*)d_in[3];
    const float* mg = (const float*)d_in[4];
    const float* mb = (const float*)d_in[5];
    const float* mw = (const float*)d_in[6];
    const float* mbi = (const float*)d_in[7];
    const float* lg = (const float*)d_in[8];
    const float* lb = (const float*)d_in[9];
    float* out = (float*)d_out;

    k_first<<<4096, 256, 0, stream>>>(pts, wf, bfirst);
    k_reduce1<<<64, 256, 0, stream>>>();
    for (int L = 0; L < 4; ++L) {
        k_fold<<<128, 256, 0, stream>>>(L, mg, mb, mw, mbi);
        if (L < 3)
            k_gemm<0><<<4096, 256, 0, stream>>>();
        else
            k_gemm<1><<<4096, 256, 0, stream>>>();
        k_reduce1<<<64, 256, 0, stream>>>();
    }
    k_lastbn<<<256, 256, 0, stream>>>(lg, lb);
    k_final<<<2048, 256, 0, stream>>>(out);
}